// Round 8
// baseline (200.774 us; speedup 1.0000x reference)
//
#include <hip/hip_runtime.h>
#include <hip/hip_fp16.h>
#include <math.h>

#define SP 32768            // 32*32*32 voxels
#define PW 38               // padded volume width (zero ring around 34^3 logical)
#define PW2 (PW*PW)         // 1444
#define PVOX (PW*PW*PW)     // 54872

typedef short bf16x8 __attribute__((ext_vector_type(8)));
typedef short s16x4 __attribute__((ext_vector_type(4)));
typedef unsigned short u16x4 __attribute__((ext_vector_type(4)));
typedef float f32x4 __attribute__((ext_vector_type(4)));

__device__ __forceinline__ unsigned short f2b(float f) {
    unsigned u = __float_as_uint(f);
    u = (u + 0x7FFFu + ((u >> 16) & 1u)) >> 16;   // RNE
    return (unsigned short)u;
}
__device__ __forceinline__ float b2f1(unsigned short s) {
    return __uint_as_float(((unsigned)s) << 16);
}

// ================= K1: prep (bf16 B^T weights) + x transpose + dwconv ==============
__global__ void k_front(const float* __restrict__ x, const float* __restrict__ dw,
                        const float* __restrict__ off_w, const float* __restrict__ mask_w,
                        const float* __restrict__ off_b, const float* __restrict__ mask_b,
                        const float* __restrict__ inp_w, const float* __restrict__ out_w,
                        unsigned short* __restrict__ WcatB, float* __restrict__ bcat,
                        unsigned short* __restrict__ inpB, unsigned short* __restrict__ outB,
                        unsigned short* __restrict__ x_tb,
                        unsigned short* __restrict__ xcb, float* __restrict__ partials) {
    int bb = blockIdx.x, tid = threadIdx.x;
    if (bb < 88) {                               // ---- weight prep ----
        int idx = bb * 256 + tid;
        int j = idx >> 6, k = idx & 63;
        if (j < 224) {
            float v = 0.f;
            if (j < 162) v = off_w[k * 162 + j];
            else if (j < 216) v = mask_w[k * 54 + (j - 162)];
            WcatB[j * 64 + k] = f2b(v);
            if (k == 0) bcat[j] = (j < 162) ? off_b[j] : (j < 216 ? mask_b[j - 162] : 0.f);
        } else if (j < 288) {
            outB[(j - 224) * 64 + k] = f2b(out_w[k * 64 + (j - 224)]);
        } else {
            inpB[(j - 288) * 64 + k] = f2b(inp_w[k * 64 + (j - 288)]);
        }
        return;
    }
    if (bb < 600) {                              // ---- x: NCDHW -> [s][c] bf16 ----
        __shared__ unsigned short tile[64][66];
        int s0 = (bb - 88) * 64;
        int row = tid >> 6, lane = tid & 63;
        for (int c = row; c < 64; c += 4)
            tile[c][lane] = f2b(x[(size_t)c * SP + s0 + lane]);
        __syncthreads();
        for (int r = row; r < 64; r += 4)
            x_tb[(size_t)(s0 + r) * 64 + lane] = tile[lane][r];
        return;
    }
    // ---- depthwise conv 3x3x3 + per-block sum/sumsq ----
    int b3 = bb - 600;
    int e = b3 * 256 + tid;
    int c = e >> 15, s = e & 32767;
    int d = s >> 10, h = (s >> 5) & 31, w = s & 31;
    const float* xs = x + (size_t)c * SP;
    const float* wt = dw + c * 27;
    float a = 0.f;
#pragma unroll
    for (int kd = 0; kd < 3; ++kd) {
        int zz = d + kd - 1; if ((unsigned)zz >= 32u) continue;
#pragma unroll
        for (int kh = 0; kh < 3; ++kh) {
            int yy = h + kh - 1; if ((unsigned)yy >= 32u) continue;
#pragma unroll
            for (int kw = 0; kw < 3; ++kw) {
                int xx = w + kw - 1; if ((unsigned)xx >= 32u) continue;
                a += xs[(zz << 10) + (yy << 5) + xx] * wt[kd * 9 + kh * 3 + kw];
            }
        }
    }
    xcb[e] = f2b(a);
    __shared__ float rs[256], rq[256];
    rs[tid] = a; rq[tid] = a * a;
    __syncthreads();
    for (int off = 128; off > 0; off >>= 1) {
        if (tid < off) { rs[tid] += rs[tid + off]; rq[tid] += rq[tid + off]; }
        __syncthreads();
    }
    if (tid == 0) {
        partials[b3 * 2 + 0] = rs[0];
        partials[b3 * 2 + 1] = rq[0];
    }
}

// ========= K2: GN+GELU -> x1b  |  MFMA inproj -> xpad (fp16)  |  ring zero =========
__global__ void k_mid(const unsigned short* __restrict__ xcb, const float* __restrict__ partials,
                      const float* __restrict__ gn_w, const float* __restrict__ gn_b,
                      unsigned short* __restrict__ x1b,
                      const unsigned short* __restrict__ x_tb,
                      const unsigned short* __restrict__ inpB,
                      const float* __restrict__ inp_b,
                      unsigned short* __restrict__ xpad) {
    int bb = blockIdx.x, tid = threadIdx.x;
    if (bb < 512) {                              // ---- GroupNorm(1,C)+GELU, transposed ----
        __shared__ float rs[256], rq[256];
        __shared__ unsigned short tile[64][66];
        float a = 0.f, b = 0.f;
        for (int i = tid; i < 8192; i += 256) { a += partials[2 * i]; b += partials[2 * i + 1]; }
        rs[tid] = a; rq[tid] = b;
        __syncthreads();
        for (int off = 128; off > 0; off >>= 1) {
            if (tid < off) { rs[tid] += rs[tid + off]; rq[tid] += rq[tid + off]; }
            __syncthreads();
        }
        const float Minv = 1.f / 2097152.f;
        float mu = rs[0] * Minv;
        float var = rq[0] * Minv - mu * mu;
        float rsq = rsqrtf(var + 1e-5f);
        int s0 = bb * 64;
        int row = tid >> 6, lane = tid & 63;
        for (int c = row; c < 64; c += 4) {
            float v = (b2f1(xcb[(size_t)c * SP + s0 + lane]) - mu) * rsq * gn_w[c] + gn_b[c];
            // gelu(tanh) = v * sigmoid(2t), t = 0.79788456*(v+0.044715 v^3)
            float t2 = 1.5957691216057308f * (v + 0.044715f * v * v * v);
            tile[c][lane] = f2b(v / (1.f + __expf(-t2)));
        }
        __syncthreads();
        for (int r = row; r < 64; r += 4)
            x1b[(size_t)(s0 + r) * 64 + lane] = tile[lane][r];
        return;
    }
    if (bb < 1024) {                             // ---- inproj: 4 waves x 16 voxels ----
        int wv = tid >> 6, lane = tid & 63;
        int quad = lane >> 4, col = lane & 15;
        int s0 = (bb - 512) * 64 + wv * 16;
        bf16x8 a0 = *(const bf16x8*)(x_tb + (size_t)(s0 + col) * 64 + quad * 8);
        bf16x8 a1 = *(const bf16x8*)(x_tb + (size_t)(s0 + col) * 64 + 32 + quad * 8);
        int vp[4];
#pragma unroll
        for (int r = 0; r < 4; ++r) {
            int s = s0 + (quad << 2) + r;        // orig voxel (d,h,w) at 38-coord +2
            vp[r] = (((s >> 10) + 2) * PW + ((s >> 5) & 31) + 2) * PW + (s & 31) + 2;
        }
#pragma unroll
        for (int nt = 0; nt < 4; ++nt) {
            int n0 = nt * 16;
            bf16x8 b0 = *(const bf16x8*)(inpB + (n0 + col) * 64 + quad * 8);
            bf16x8 b1 = *(const bf16x8*)(inpB + (n0 + col) * 64 + 32 + quad * 8);
            f32x4 c = {0.f, 0.f, 0.f, 0.f};
            c = __builtin_amdgcn_mfma_f32_16x16x32_bf16(a0, b0, c, 0, 0, 0);
            c = __builtin_amdgcn_mfma_f32_16x16x32_bf16(a1, b1, c, 0, 0, 0);
            float bq = inp_b[n0 + col];
#pragma unroll
            for (int r = 0; r < 4; ++r)
                xpad[(size_t)vp[r] * 64 + n0 + col] =
                    __half_as_ushort(__float2half(c[r] + bq));
        }
        return;
    }
    // ---- ring zero (fp16): 16 voxels x 16 8-byte slots per 256 threads, 4 iters ----
    int cblk = bb - 1024;
    int j = tid >> 4, c4 = tid & 15;
    u16x4 z = {0, 0, 0, 0};
#pragma unroll
    for (int k = 0; k < 4; ++k) {
        int v = cblk * 64 + k * 16 + j;
        if (v >= PVOX) break;
        int zz = v / PW2, r = v - zz * PW2, yy = r / PW, xx = r - yy * PW;
        if (zz < 2 || zz > 33 || yy < 2 || yy > 33 || xx < 2 || xx > 33)
            *(u16x4*)(xpad + (size_t)v * 64 + c4 * 4) = z;
    }
}

// ========= K3: main — 4 waves / 16 voxels per block; packed-fp16 trilinear =========
__global__ void __launch_bounds__(256, 8) k_main(const unsigned short* __restrict__ x1b,
                                                 const unsigned short* __restrict__ xpad,
                                                 const unsigned short* __restrict__ WcatB,
                                                 const float* __restrict__ bcat,
                                                 const unsigned short* __restrict__ outB,
                                                 const float* __restrict__ out_b,
                                                 float* __restrict__ out) {
    __shared__ float om_s[16 * 225];             // offsets+masks; reused as obuf in epilogue
    __shared__ unsigned short smb[16 * 72];      // sampled accum, bf16
    int tid = threadIdx.x, wv = tid >> 6, lane = tid & 63;
    int quad = lane >> 4, col = lane & 15;
    // XCD swizzle: blocks sharing (blk&7) land on one XCD, contiguous 4096-voxel slab
    int sb = ((blockIdx.x & 7) << 8) | (blockIdx.x >> 3);
    int s0 = sb * 16;                            // 16 voxels per block
    // ---- phase 1: offset+mask GEMM (16x64)@(64x224), nt-tiles split across waves ----
    bf16x8 a0 = *(const bf16x8*)(x1b + (size_t)(s0 + col) * 64 + quad * 8);
    bf16x8 a1 = *(const bf16x8*)(x1b + (size_t)(s0 + col) * 64 + 32 + quad * 8);
    for (int jt = wv; jt < 14; jt += 4) {
        int n0 = jt * 16;
        bf16x8 b0 = *(const bf16x8*)(WcatB + (n0 + col) * 64 + quad * 8);
        bf16x8 b1 = *(const bf16x8*)(WcatB + (n0 + col) * 64 + 32 + quad * 8);
        f32x4 c = {0.f, 0.f, 0.f, 0.f};
        c = __builtin_amdgcn_mfma_f32_16x16x32_bf16(a0, b0, c, 0, 0, 0);
        c = __builtin_amdgcn_mfma_f32_16x16x32_bf16(a1, b1, c, 0, 0, 0);
        float bb = bcat[n0 + col];
#pragma unroll
        for (int r = 0; r < 4; ++r)
            om_s[(quad * 4 + r) * 225 + n0 + col] = c[r] + bb;
    }
    __syncthreads();
    // ---- phase 2: softmax over 27 pts, 32 rows = 16 voxels x 2 groups ----
    if (tid < 32) {
        int v = tid >> 1, g = tid & 1;
        float* m = &om_s[v * 225 + 162 + g * 27];
        float mx = m[0];
#pragma unroll
        for (int p = 1; p < 27; ++p) mx = fmaxf(mx, m[p]);
        float e[27]; float sm = 0.f;
#pragma unroll
        for (int p = 0; p < 27; ++p) { e[p] = __expf(m[p] - mx); sm += e[p]; }
        float inv = 1.f / sm;
#pragma unroll
        for (int p = 0; p < 27; ++p) m[p] = e[p] * inv;
    }
    __syncthreads();
    // ---- phase 3: sampling; wave wv handles voxels wv*4..wv*4+3, 4 ch per lane ----
    {
        int v = (wv << 2) + quad, cq = col, gg = col >> 3;
        int sv = s0 + v;
        int d = sv >> 10, h = (sv >> 5) & 31, w = sv & 31;
        float zb = (float)(d + 1), yb = (float)(h + 1), xb = (float)(w + 1);
        const float* orow = &om_s[v * 225 + gg * 81];
        const float* mrow = &om_s[v * 225 + 162 + gg * 27];
        const char* volc = (const char*)xpad + cq * 8;      // 4 fp16 channels
        f32x4 acc = {0.f, 0.f, 0.f, 0.f};
        int p = 0;
#pragma unroll
        for (int pz = 0; pz < 3; ++pz) {
#pragma unroll
            for (int py = 0; py < 3; ++py) {
#pragma unroll
                for (int px = 0; px < 3; ++px) {
                    float ox = orow[p * 3 + 0], oy = orow[p * 3 + 1], oz = orow[p * 3 + 2];
                    float mk = mrow[p];
                    float ix = __builtin_fmaf(0.25f, ox, xb + (float)px);
                    float iy = __builtin_fmaf(0.5f, oy, yb + (float)py);
                    float iz = __builtin_fmaf(0.5f, oz, zb + (float)pz);
                    // clamp to [0,36]: OOB samples land wholly in the zero ring
                    ix = fminf(fmaxf(ix, 0.f), 36.f);
                    iy = fminf(fmaxf(iy, 0.f), 36.f);
                    iz = fminf(fmaxf(iz, 0.f), 36.f);
                    float xf = floorf(ix), yf = floorf(iy), zf = floorf(iz);
                    float fx = ix - xf, fy = iy - yf, fz = iz - zf;
                    float fi = __builtin_fmaf(zf, (float)PW2, __builtin_fmaf(yf, (float)PW, xf));
                    int ib = ((int)fi) << 7;     // 128 B per voxel row (fp16)
                    const char* base = volc + ib;
                    uint2 r000 = *(const uint2*)(base);
                    uint2 r001 = *(const uint2*)(base + 128);
                    uint2 r010 = *(const uint2*)(base + PW * 128);
                    uint2 r011 = *(const uint2*)(base + PW * 128 + 128);
                    uint2 r100 = *(const uint2*)(base + PW2 * 128);
                    uint2 r101 = *(const uint2*)(base + PW2 * 128 + 128);
                    uint2 r110 = *(const uint2*)(base + (PW2 + PW) * 128);
                    uint2 r111 = *(const uint2*)(base + (PW2 + PW) * 128 + 128);
                    __half2 fx2 = __float2half2_rn(fx);
                    __half2 fy2 = __float2half2_rn(fy);
                    __half2 fz2 = __float2half2_rn(fz);
                    #define H2(u) (*reinterpret_cast<const __half2*>(&(u)))
                    __half2 t00a = __hfma2(fx2, __hsub2(H2(r001.x), H2(r000.x)), H2(r000.x));
                    __half2 t00b = __hfma2(fx2, __hsub2(H2(r001.y), H2(r000.y)), H2(r000.y));
                    __half2 t01a = __hfma2(fx2, __hsub2(H2(r011.x), H2(r010.x)), H2(r010.x));
                    __half2 t01b = __hfma2(fx2, __hsub2(H2(r011.y), H2(r010.y)), H2(r010.y));
                    __half2 t10a = __hfma2(fx2, __hsub2(H2(r101.x), H2(r100.x)), H2(r100.x));
                    __half2 t10b = __hfma2(fx2, __hsub2(H2(r101.y), H2(r100.y)), H2(r100.y));
                    __half2 t11a = __hfma2(fx2, __hsub2(H2(r111.x), H2(r110.x)), H2(r110.x));
                    __half2 t11b = __hfma2(fx2, __hsub2(H2(r111.y), H2(r110.y)), H2(r110.y));
                    #undef H2
                    __half2 u0a = __hfma2(fy2, __hsub2(t01a, t00a), t00a);
                    __half2 u0b = __hfma2(fy2, __hsub2(t01b, t00b), t00b);
                    __half2 u1a = __hfma2(fy2, __hsub2(t11a, t10a), t10a);
                    __half2 u1b = __hfma2(fy2, __hsub2(t11b, t10b), t10b);
                    __half2 ra = __hfma2(fz2, __hsub2(u1a, u0a), u0a);
                    __half2 rb = __hfma2(fz2, __hsub2(u1b, u0b), u0b);
                    float2 fa = __half22float2(ra), fb = __half22float2(rb);
                    acc[0] = __builtin_fmaf(mk, fa.x, acc[0]);
                    acc[1] = __builtin_fmaf(mk, fa.y, acc[1]);
                    acc[2] = __builtin_fmaf(mk, fb.x, acc[2]);
                    acc[3] = __builtin_fmaf(mk, fb.y, acc[3]);
                    ++p;
                }
            }
        }
        s16x4 sb4;
        sb4[0] = (short)f2b(acc[0]); sb4[1] = (short)f2b(acc[1]);
        sb4[2] = (short)f2b(acc[2]); sb4[3] = (short)f2b(acc[3]);
        *(s16x4*)(smb + v * 72 + cq * 4) = sb4;
    }
    __syncthreads();
    // ---- phase 4: out projection (16x64)@(64x64); wave wv does nt tile wv ----
    {
        float* obuf = om_s;                      // alias: om_s is dead now
        int n0 = wv * 16;
        bf16x8 oa0 = *(const bf16x8*)(smb + col * 72 + quad * 8);
        bf16x8 oa1 = *(const bf16x8*)(smb + col * 72 + 32 + quad * 8);
        bf16x8 b0 = *(const bf16x8*)(outB + (n0 + col) * 64 + quad * 8);
        bf16x8 b1 = *(const bf16x8*)(outB + (n0 + col) * 64 + 32 + quad * 8);
        f32x4 c = {0.f, 0.f, 0.f, 0.f};
        c = __builtin_amdgcn_mfma_f32_16x16x32_bf16(oa0, b0, c, 0, 0, 0);
        c = __builtin_amdgcn_mfma_f32_16x16x32_bf16(oa1, b1, c, 0, 0, 0);
        float bb = out_b[n0 + col];
#pragma unroll
        for (int r = 0; r < 4; ++r)
            obuf[(quad * 4 + r) * 64 + n0 + col] = c[r] + bb;
    }
    __syncthreads();
    // ---- phase 5: coalesced output store (16 rows x 256 B contiguous) ----
    {
        const float* obuf = om_s;
#pragma unroll
        for (int i = 0; i < 4; ++i) {
            int idx = i * 256 + tid;
            out[(size_t)(s0 + (idx >> 6)) * 64 + (idx & 63)] = obuf[idx];
        }
    }
}

extern "C" void kernel_launch(void* const* d_in, const int* in_sizes, int n_in,
                              void* d_out, int out_size, void* d_ws, size_t ws_size,
                              hipStream_t stream) {
    const float* x      = (const float*)d_in[0];
    const float* dw_w   = (const float*)d_in[1];
    const float* gn_w   = (const float*)d_in[2];
    const float* gn_b   = (const float*)d_in[3];
    const float* inp_w  = (const float*)d_in[4];
    const float* inp_b  = (const float*)d_in[5];
    const float* off_w  = (const float*)d_in[6];
    const float* off_b  = (const float*)d_in[7];
    const float* mask_w = (const float*)d_in[8];
    const float* mask_b = (const float*)d_in[9];
    const float* out_w  = (const float*)d_in[10];
    const float* out_b  = (const float*)d_in[11];

    char* B = (char*)d_ws;
    float*          partials = (float*)(B + 256);                // 64 KB
    unsigned short* xcb      = (unsigned short*)(B + 65792);     // 4 MB (bf16)
    unsigned short* x1b      = (unsigned short*)(B + 8454400);   // 4 MB
    unsigned short* x_tb     = (unsigned short*)(B + 12648704);  // 4 MB
    unsigned short* xpad     = (unsigned short*)(B + 16843008);  // 7.02 MB (fp16)
    unsigned short* WcatB    = (unsigned short*)(B + 30890240);  // 28 KB
    float*          bcat     = (float*)(B + 30918912);           // 1 KB
    unsigned short* inpB     = (unsigned short*)(B + 30919936);  // 8 KB
    unsigned short* outB     = (unsigned short*)(B + 30928128);  // 8 KB
    float* out = (float*)d_out;

    k_front<<<8792, 256, 0, stream>>>(x, dw_w, off_w, mask_w, off_b, mask_b,
                                      inp_w, out_w, WcatB, bcat, inpB, outB,
                                      x_tb, xcb, partials);
    k_mid<<<512 + 512 + 858, 256, 0, stream>>>(xcb, partials, gn_w, gn_b, x1b,
                                               x_tb, inpB, inp_b, xpad);
    k_main<<<2048, 256, 0, stream>>>(x1b, xpad, WcatB, bcat, outB, out_b, out);
}

// Round 9
// 176.561 us; speedup vs baseline: 1.1371x; 1.1371x over previous
//
#include <hip/hip_runtime.h>
#include <hip/hip_fp16.h>
#include <math.h>

#define SP 32768            // 32*32*32 voxels
#define PW 38               // padded volume width (zero ring around 34^3 logical)
#define PW2 (PW*PW)         // 1444
#define PVOX (PW*PW*PW)     // 54872
#define OMS 220             // om_s row stride (floats); 32*220*4 + 32*72*2 = 32 KB exactly

typedef short bf16x8 __attribute__((ext_vector_type(8)));
typedef short s16x4 __attribute__((ext_vector_type(4)));
typedef unsigned short u16x4 __attribute__((ext_vector_type(4)));
typedef float f32x4 __attribute__((ext_vector_type(4)));

__device__ __forceinline__ unsigned short f2b(float f) {
    unsigned u = __float_as_uint(f);
    u = (u + 0x7FFFu + ((u >> 16) & 1u)) >> 16;   // RNE
    return (unsigned short)u;
}
__device__ __forceinline__ float b2f1(unsigned short s) {
    return __uint_as_float(((unsigned)s) << 16);
}
__device__ __forceinline__ __half2 h2(unsigned u) {
    return *reinterpret_cast<__half2*>(&u);
}

// ================= K1: prep (bf16 B^T weights) + x transpose + dwconv ==============
__global__ void k_front(const float* __restrict__ x, const float* __restrict__ dw,
                        const float* __restrict__ off_w, const float* __restrict__ mask_w,
                        const float* __restrict__ off_b, const float* __restrict__ mask_b,
                        const float* __restrict__ inp_w, const float* __restrict__ out_w,
                        unsigned short* __restrict__ WcatB, float* __restrict__ bcat,
                        unsigned short* __restrict__ inpB, unsigned short* __restrict__ outB,
                        unsigned short* __restrict__ x_tb,
                        unsigned short* __restrict__ xcb, float* __restrict__ partials) {
    int bb = blockIdx.x, tid = threadIdx.x;
    if (bb < 88) {                               // ---- weight prep ----
        int idx = bb * 256 + tid;
        int j = idx >> 6, k = idx & 63;
        if (j < 224) {
            float v = 0.f;
            if (j < 162) v = off_w[k * 162 + j];
            else if (j < 216) v = mask_w[k * 54 + (j - 162)];
            WcatB[j * 64 + k] = f2b(v);
            if (k == 0) bcat[j] = (j < 162) ? off_b[j] : (j < 216 ? mask_b[j - 162] : 0.f);
        } else if (j < 288) {
            outB[(j - 224) * 64 + k] = f2b(out_w[k * 64 + (j - 224)]);
        } else {
            inpB[(j - 288) * 64 + k] = f2b(inp_w[k * 64 + (j - 288)]);
        }
        return;
    }
    if (bb < 600) {                              // ---- x: NCDHW -> [s][c] bf16 ----
        __shared__ unsigned short tile[64][66];
        int s0 = (bb - 88) * 64;
        int row = tid >> 6, lane = tid & 63;
        for (int c = row; c < 64; c += 4)
            tile[c][lane] = f2b(x[(size_t)c * SP + s0 + lane]);
        __syncthreads();
        for (int r = row; r < 64; r += 4)
            x_tb[(size_t)(s0 + r) * 64 + lane] = tile[lane][r];
        return;
    }
    // ---- depthwise conv 3x3x3 + per-block sum/sumsq ----
    int b3 = bb - 600;
    int e = b3 * 256 + tid;
    int c = e >> 15, s = e & 32767;
    int d = s >> 10, h = (s >> 5) & 31, w = s & 31;
    const float* xs = x + (size_t)c * SP;
    const float* wt = dw + c * 27;
    float a = 0.f;
#pragma unroll
    for (int kd = 0; kd < 3; ++kd) {
        int zz = d + kd - 1; if ((unsigned)zz >= 32u) continue;
#pragma unroll
        for (int kh = 0; kh < 3; ++kh) {
            int yy = h + kh - 1; if ((unsigned)yy >= 32u) continue;
#pragma unroll
            for (int kw = 0; kw < 3; ++kw) {
                int xx = w + kw - 1; if ((unsigned)xx >= 32u) continue;
                a += xs[(zz << 10) + (yy << 5) + xx] * wt[kd * 9 + kh * 3 + kw];
            }
        }
    }
    xcb[e] = f2b(a);
    __shared__ float rs[256], rq[256];
    rs[tid] = a; rq[tid] = a * a;
    __syncthreads();
    for (int off = 128; off > 0; off >>= 1) {
        if (tid < off) { rs[tid] += rs[tid + off]; rq[tid] += rq[tid + off]; }
        __syncthreads();
    }
    if (tid == 0) {
        partials[b3 * 2 + 0] = rs[0];
        partials[b3 * 2 + 1] = rq[0];
    }
}

// ========= K2: GN+GELU -> x1b  |  MFMA inproj -> xpad (fp16)  |  ring zero =========
__global__ void k_mid(const unsigned short* __restrict__ xcb, const float* __restrict__ partials,
                      const float* __restrict__ gn_w, const float* __restrict__ gn_b,
                      unsigned short* __restrict__ x1b,
                      const unsigned short* __restrict__ x_tb,
                      const unsigned short* __restrict__ inpB,
                      const float* __restrict__ inp_b,
                      unsigned short* __restrict__ xpad) {
    int bb = blockIdx.x, tid = threadIdx.x;
    if (bb < 512) {                              // ---- GroupNorm(1,C)+GELU, transposed ----
        __shared__ float rs[256], rq[256];
        __shared__ unsigned short tile[64][66];
        float a = 0.f, b = 0.f;
        for (int i = tid; i < 8192; i += 256) { a += partials[2 * i]; b += partials[2 * i + 1]; }
        rs[tid] = a; rq[tid] = b;
        __syncthreads();
        for (int off = 128; off > 0; off >>= 1) {
            if (tid < off) { rs[tid] += rs[tid + off]; rq[tid] += rq[tid + off]; }
            __syncthreads();
        }
        const float Minv = 1.f / 2097152.f;
        float mu = rs[0] * Minv;
        float var = rq[0] * Minv - mu * mu;
        float rsq = rsqrtf(var + 1e-5f);
        int s0 = bb * 64;
        int row = tid >> 6, lane = tid & 63;
        for (int c = row; c < 64; c += 4) {
            float v = (b2f1(xcb[(size_t)c * SP + s0 + lane]) - mu) * rsq * gn_w[c] + gn_b[c];
            // gelu(tanh) = v * sigmoid(2t), t = 0.79788456*(v+0.044715 v^3)
            float t2 = 1.5957691216057308f * (v + 0.044715f * v * v * v);
            tile[c][lane] = f2b(v / (1.f + __expf(-t2)));
        }
        __syncthreads();
        for (int r = row; r < 64; r += 4)
            x1b[(size_t)(s0 + r) * 64 + lane] = tile[lane][r];
        return;
    }
    if (bb < 1024) {                             // ---- inproj: 4 waves x 16 voxels ----
        int wv = tid >> 6, lane = tid & 63;
        int quad = lane >> 4, col = lane & 15;
        int s0 = (bb - 512) * 64 + wv * 16;
        bf16x8 a0 = *(const bf16x8*)(x_tb + (size_t)(s0 + col) * 64 + quad * 8);
        bf16x8 a1 = *(const bf16x8*)(x_tb + (size_t)(s0 + col) * 64 + 32 + quad * 8);
        int vp[4];
#pragma unroll
        for (int r = 0; r < 4; ++r) {
            int s = s0 + (quad << 2) + r;        // orig voxel (d,h,w) at 38-coord +2
            vp[r] = (((s >> 10) + 2) * PW + ((s >> 5) & 31) + 2) * PW + (s & 31) + 2;
        }
#pragma unroll
        for (int nt = 0; nt < 4; ++nt) {
            int n0 = nt * 16;
            bf16x8 b0 = *(const bf16x8*)(inpB + (n0 + col) * 64 + quad * 8);
            bf16x8 b1 = *(const bf16x8*)(inpB + (n0 + col) * 64 + 32 + quad * 8);
            f32x4 c = {0.f, 0.f, 0.f, 0.f};
            c = __builtin_amdgcn_mfma_f32_16x16x32_bf16(a0, b0, c, 0, 0, 0);
            c = __builtin_amdgcn_mfma_f32_16x16x32_bf16(a1, b1, c, 0, 0, 0);
            float bq = inp_b[n0 + col];
#pragma unroll
            for (int r = 0; r < 4; ++r)
                xpad[(size_t)vp[r] * 64 + n0 + col] =
                    __half_as_ushort(__float2half(c[r] + bq));
        }
        return;
    }
    // ---- ring zero (fp16): 16 voxels x 16 8-byte slots per 256 threads, 4 iters ----
    int cblk = bb - 1024;
    int j = tid >> 4, c4 = tid & 15;
    u16x4 z = {0, 0, 0, 0};
#pragma unroll
    for (int k = 0; k < 4; ++k) {
        int v = cblk * 64 + k * 16 + j;
        if (v >= PVOX) break;
        int zz = v / PW2, r = v - zz * PW2, yy = r / PW, xx = r - yy * PW;
        if (zz < 2 || zz > 33 || yy < 2 || yy > 33 || xx < 2 || xx > 33)
            *(u16x4*)(xpad + (size_t)v * 64 + c4 * 4) = z;
    }
}

// ========= K3: main — 32 voxels/block, 8 ch/lane dwordx4 sampling =========
__global__ void __launch_bounds__(256, 4) k_main(const unsigned short* __restrict__ x1b,
                                                 const unsigned short* __restrict__ xpad,
                                                 const unsigned short* __restrict__ WcatB,
                                                 const float* __restrict__ bcat,
                                                 const unsigned short* __restrict__ outB,
                                                 const float* __restrict__ out_b,
                                                 float* __restrict__ out) {
    __shared__ float om_s[32 * OMS];             // offsets+masks; reused as obuf in epilogue
    __shared__ unsigned short smb[32 * 72];      // sampled accum, bf16
    int tid = threadIdx.x, wv = tid >> 6, lane = tid & 63;
    int quad = lane >> 4, col = lane & 15;
    // XCD swizzle: blocks sharing (blk&7) land on one XCD, contiguous 4096-voxel slab
    int sb = ((blockIdx.x & 7) << 7) | (blockIdx.x >> 3);
    int s0 = sb * 32;                            // 32 voxels per block
    // ---- phase 1: offset+mask GEMM (32x64)@(64x224); wave does row-half rh, 7 jt tiles ----
    {
        int rh = wv & 1;
        bf16x8 a0 = *(const bf16x8*)(x1b + (size_t)(s0 + rh * 16 + col) * 64 + quad * 8);
        bf16x8 a1 = *(const bf16x8*)(x1b + (size_t)(s0 + rh * 16 + col) * 64 + 32 + quad * 8);
        for (int jt = (wv >> 1); jt < 14; jt += 2) {
            int n0 = jt * 16;
            bf16x8 b0 = *(const bf16x8*)(WcatB + (n0 + col) * 64 + quad * 8);
            bf16x8 b1 = *(const bf16x8*)(WcatB + (n0 + col) * 64 + 32 + quad * 8);
            f32x4 c = {0.f, 0.f, 0.f, 0.f};
            c = __builtin_amdgcn_mfma_f32_16x16x32_bf16(a0, b0, c, 0, 0, 0);
            c = __builtin_amdgcn_mfma_f32_16x16x32_bf16(a1, b1, c, 0, 0, 0);
            float bb = bcat[n0 + col];
#pragma unroll
            for (int r = 0; r < 4; ++r)
                om_s[(rh * 16 + quad * 4 + r) * OMS + n0 + col] = c[r] + bb;
        }
    }
    __syncthreads();
    // ---- phase 2: softmax over 27 pts, 64 rows = 32 voxels x 2 groups ----
    if (tid < 64) {
        int v = tid >> 1, g = tid & 1;
        float* m = &om_s[v * OMS + 162 + g * 27];
        float mx = m[0];
#pragma unroll
        for (int p = 1; p < 27; ++p) mx = fmaxf(mx, m[p]);
        float e[27]; float sm = 0.f;
#pragma unroll
        for (int p = 0; p < 27; ++p) { e[p] = __expf(m[p] - mx); sm += e[p]; }
        float inv = 1.f / sm;
#pragma unroll
        for (int p = 0; p < 27; ++p) m[p] = e[p] * inv;
    }
    __syncthreads();
    // ---- phase 3: sampling; wave wv: voxels wv*8..wv*8+7, 8 fp16 ch/lane (dwordx4) ----
    {
        int v = (wv << 3) | (lane >> 3);         // local voxel 0..31
        int oct = lane & 7, gg = oct >> 2;       // channels oct*8..oct*8+7
        int sv = s0 + v;
        int d = sv >> 10, h = (sv >> 5) & 31, w = sv & 31;
        float zb = (float)(d + 1), yb = (float)(h + 1), xb = (float)(w + 1);
        const float* orow = &om_s[v * OMS + gg * 81];
        const float* mrow = &om_s[v * OMS + 162 + gg * 27];
        const char* volc = (const char*)xpad + oct * 16;    // 8 fp16 channels
        float acc[8] = {0.f, 0.f, 0.f, 0.f, 0.f, 0.f, 0.f, 0.f};
        int p = 0;
#pragma unroll
        for (int pz = 0; pz < 3; ++pz) {
#pragma unroll
            for (int py = 0; py < 3; ++py) {
#pragma unroll
                for (int px = 0; px < 3; ++px) {
                    float ox = orow[p * 3 + 0], oy = orow[p * 3 + 1], oz = orow[p * 3 + 2];
                    float mk = mrow[p];
                    float ix = __builtin_fmaf(0.25f, ox, xb + (float)px);
                    float iy = __builtin_fmaf(0.5f, oy, yb + (float)py);
                    float iz = __builtin_fmaf(0.5f, oz, zb + (float)pz);
                    // clamp to [0,36]: OOB samples land wholly in the zero ring
                    ix = fminf(fmaxf(ix, 0.f), 36.f);
                    iy = fminf(fmaxf(iy, 0.f), 36.f);
                    iz = fminf(fmaxf(iz, 0.f), 36.f);
                    float xf = floorf(ix), yf = floorf(iy), zf = floorf(iz);
                    float fx = ix - xf, fy = iy - yf, fz = iz - zf;
                    float fi = __builtin_fmaf(zf, (float)PW2, __builtin_fmaf(yf, (float)PW, xf));
                    int ib = ((int)fi) << 7;     // 128 B per voxel row (fp16)
                    const char* base = volc + ib;
                    uint4 r000 = *(const uint4*)(base);
                    uint4 r001 = *(const uint4*)(base + 128);
                    uint4 r010 = *(const uint4*)(base + PW * 128);
                    uint4 r011 = *(const uint4*)(base + PW * 128 + 128);
                    uint4 r100 = *(const uint4*)(base + PW2 * 128);
                    uint4 r101 = *(const uint4*)(base + PW2 * 128 + 128);
                    uint4 r110 = *(const uint4*)(base + (PW2 + PW) * 128);
                    uint4 r111 = *(const uint4*)(base + (PW2 + PW) * 128 + 128);
                    __half2 fx2 = __float2half2_rn(fx);
                    __half2 fy2 = __float2half2_rn(fy);
                    __half2 fz2 = __float2half2_rn(fz);
                    #define TRI(comp, ci)                                                   \
                    {                                                                       \
                        __half2 t0 = __hfma2(fx2, __hsub2(h2(r001.comp), h2(r000.comp)), h2(r000.comp)); \
                        __half2 t1 = __hfma2(fx2, __hsub2(h2(r011.comp), h2(r010.comp)), h2(r010.comp)); \
                        __half2 t2 = __hfma2(fx2, __hsub2(h2(r101.comp), h2(r100.comp)), h2(r100.comp)); \
                        __half2 t3 = __hfma2(fx2, __hsub2(h2(r111.comp), h2(r110.comp)), h2(r110.comp)); \
                        __half2 u0 = __hfma2(fy2, __hsub2(t1, t0), t0);                     \
                        __half2 u1 = __hfma2(fy2, __hsub2(t3, t2), t2);                     \
                        __half2 rr = __hfma2(fz2, __hsub2(u1, u0), u0);                     \
                        float2 ff = __half22float2(rr);                                     \
                        acc[2 * ci + 0] = __builtin_fmaf(mk, ff.x, acc[2 * ci + 0]);        \
                        acc[2 * ci + 1] = __builtin_fmaf(mk, ff.y, acc[2 * ci + 1]);        \
                    }
                    TRI(x, 0) TRI(y, 1) TRI(z, 2) TRI(w, 3)
                    #undef TRI
                    ++p;
                }
            }
        }
        bf16x8 sb8;
#pragma unroll
        for (int k = 0; k < 8; ++k) sb8[k] = (short)f2b(acc[k]);
        *(bf16x8*)(smb + v * 72 + oct * 8) = sb8;
    }
    __syncthreads();
    // ---- phase 4: out projection (32x64)@(64x64); 8 tiles over 4 waves ----
    {
        float* obuf = om_s;                      // alias: om_s is dead now
#pragma unroll
        for (int t = 0; t < 2; ++t) {
            int tile = wv * 2 + t;
            int rh = tile >> 2, n0 = (tile & 3) * 16;
            bf16x8 oa0 = *(const bf16x8*)(smb + (rh * 16 + col) * 72 + quad * 8);
            bf16x8 oa1 = *(const bf16x8*)(smb + (rh * 16 + col) * 72 + 32 + quad * 8);
            bf16x8 b0 = *(const bf16x8*)(outB + (n0 + col) * 64 + quad * 8);
            bf16x8 b1 = *(const bf16x8*)(outB + (n0 + col) * 64 + 32 + quad * 8);
            f32x4 c = {0.f, 0.f, 0.f, 0.f};
            c = __builtin_amdgcn_mfma_f32_16x16x32_bf16(oa0, b0, c, 0, 0, 0);
            c = __builtin_amdgcn_mfma_f32_16x16x32_bf16(oa1, b1, c, 0, 0, 0);
            float bb = out_b[n0 + col];
#pragma unroll
            for (int r = 0; r < 4; ++r)
                obuf[(rh * 16 + quad * 4 + r) * 64 + n0 + col] = c[r] + bb;
        }
    }
    __syncthreads();
    // ---- phase 5: coalesced output store (32 rows x 256 B contiguous) ----
    {
        const float* obuf = om_s;
#pragma unroll
        for (int i = 0; i < 8; ++i) {
            int idx = i * 256 + tid;
            out[(size_t)(s0 + (idx >> 6)) * 64 + (idx & 63)] = obuf[idx];
        }
    }
}

extern "C" void kernel_launch(void* const* d_in, const int* in_sizes, int n_in,
                              void* d_out, int out_size, void* d_ws, size_t ws_size,
                              hipStream_t stream) {
    const float* x      = (const float*)d_in[0];
    const float* dw_w   = (const float*)d_in[1];
    const float* gn_w   = (const float*)d_in[2];
    const float* gn_b   = (const float*)d_in[3];
    const float* inp_w  = (const float*)d_in[4];
    const float* inp_b  = (const float*)d_in[5];
    const float* off_w  = (const float*)d_in[6];
    const float* off_b  = (const float*)d_in[7];
    const float* mask_w = (const float*)d_in[8];
    const float* mask_b = (const float*)d_in[9];
    const float* out_w  = (const float*)d_in[10];
    const float* out_b  = (const float*)d_in[11];

    char* B = (char*)d_ws;
    float*          partials = (float*)(B + 256);                // 64 KB
    unsigned short* xcb      = (unsigned short*)(B + 65792);     // 4 MB (bf16)
    unsigned short* x1b      = (unsigned short*)(B + 8454400);   // 4 MB
    unsigned short* x_tb     = (unsigned short*)(B + 12648704);  // 4 MB
    unsigned short* xpad     = (unsigned short*)(B + 16843008);  // 7.02 MB (fp16)
    unsigned short* WcatB    = (unsigned short*)(B + 30890240);  // 28 KB
    float*          bcat     = (float*)(B + 30918912);           // 1 KB
    unsigned short* inpB     = (unsigned short*)(B + 30919936);  // 8 KB
    unsigned short* outB     = (unsigned short*)(B + 30928128);  // 8 KB
    float* out = (float*)d_out;

    k_front<<<8792, 256, 0, stream>>>(x, dw_w, off_w, mask_w, off_b, mask_b,
                                      inp_w, out_w, WcatB, bcat, inpB, outB,
                                      x_tb, xcb, partials);
    k_mid<<<512 + 512 + 858, 256, 0, stream>>>(xcb, partials, gn_w, gn_b, x1b,
                                               x_tb, inpB, inp_b, xpad);
    k_main<<<1024, 256, 0, stream>>>(x1b, xpad, WcatB, bcat, outB, out_b, out);
}

// Round 10
// 175.932 us; speedup vs baseline: 1.1412x; 1.0036x over previous
//
#include <hip/hip_runtime.h>
#include <hip/hip_fp16.h>
#include <math.h>

#define SP 32768            // 32*32*32 voxels
#define PW 38               // padded volume width (zero ring around 34^3 logical)
#define PW2 (PW*PW)         // 1444
#define PVOX (PW*PW*PW)     // 54872
#define OMS 228             // om_s row stride (floats): 28-pt padded offs(2*84) + masks(2*28)

typedef short bf16x8 __attribute__((ext_vector_type(8)));
typedef unsigned short u16x4 __attribute__((ext_vector_type(4)));
typedef float f32x4 __attribute__((ext_vector_type(4)));

__device__ __forceinline__ unsigned short f2b(float f) {
    unsigned u = __float_as_uint(f);
    u = (u + 0x7FFFu + ((u >> 16) & 1u)) >> 16;   // RNE
    return (unsigned short)u;
}
__device__ __forceinline__ float b2f1(unsigned short s) {
    return __uint_as_float(((unsigned)s) << 16);
}
__device__ __forceinline__ __half2 h2(unsigned u) {
    return *reinterpret_cast<__half2*>(&u);
}

// ================= K1: prep (bf16 B^T weights) + x transpose + dwconv ==============
__global__ void k_front(const float* __restrict__ x, const float* __restrict__ dw,
                        const float* __restrict__ off_w, const float* __restrict__ mask_w,
                        const float* __restrict__ off_b, const float* __restrict__ mask_b,
                        const float* __restrict__ inp_w, const float* __restrict__ out_w,
                        unsigned short* __restrict__ WcatB, float* __restrict__ bcat,
                        unsigned short* __restrict__ inpB, unsigned short* __restrict__ outB,
                        unsigned short* __restrict__ x_tb,
                        unsigned short* __restrict__ xcb, float* __restrict__ partials) {
    int bb = blockIdx.x, tid = threadIdx.x;
    if (bb < 88) {                               // ---- weight prep ----
        int idx = bb * 256 + tid;
        int j = idx >> 6, k = idx & 63;
        if (j < 224) {
            float v = 0.f;
            if (j < 162) v = off_w[k * 162 + j];
            else if (j < 216) v = mask_w[k * 54 + (j - 162)];
            WcatB[j * 64 + k] = f2b(v);
            if (k == 0) bcat[j] = (j < 162) ? off_b[j] : (j < 216 ? mask_b[j - 162] : 0.f);
        } else if (j < 288) {
            outB[(j - 224) * 64 + k] = f2b(out_w[k * 64 + (j - 224)]);
        } else {
            inpB[(j - 288) * 64 + k] = f2b(inp_w[k * 64 + (j - 288)]);
        }
        return;
    }
    if (bb < 600) {                              // ---- x: NCDHW -> [s][c] bf16 ----
        __shared__ unsigned short tile[64][66];
        int s0 = (bb - 88) * 64;
        int row = tid >> 6, lane = tid & 63;
        for (int c = row; c < 64; c += 4)
            tile[c][lane] = f2b(x[(size_t)c * SP + s0 + lane]);
        __syncthreads();
        for (int r = row; r < 64; r += 4)
            x_tb[(size_t)(s0 + r) * 64 + lane] = tile[lane][r];
        return;
    }
    // ---- depthwise conv 3x3x3 + per-block sum/sumsq ----
    int b3 = bb - 600;
    int e = b3 * 256 + tid;
    int c = e >> 15, s = e & 32767;
    int d = s >> 10, h = (s >> 5) & 31, w = s & 31;
    const float* xs = x + (size_t)c * SP;
    const float* wt = dw + c * 27;
    float a = 0.f;
#pragma unroll
    for (int kd = 0; kd < 3; ++kd) {
        int zz = d + kd - 1; if ((unsigned)zz >= 32u) continue;
#pragma unroll
        for (int kh = 0; kh < 3; ++kh) {
            int yy = h + kh - 1; if ((unsigned)yy >= 32u) continue;
#pragma unroll
            for (int kw = 0; kw < 3; ++kw) {
                int xx = w + kw - 1; if ((unsigned)xx >= 32u) continue;
                a += xs[(zz << 10) + (yy << 5) + xx] * wt[kd * 9 + kh * 3 + kw];
            }
        }
    }
    xcb[e] = f2b(a);
    __shared__ float rs[256], rq[256];
    rs[tid] = a; rq[tid] = a * a;
    __syncthreads();
    for (int off = 128; off > 0; off >>= 1) {
        if (tid < off) { rs[tid] += rs[tid + off]; rq[tid] += rq[tid + off]; }
        __syncthreads();
    }
    if (tid == 0) {
        partials[b3 * 2 + 0] = rs[0];
        partials[b3 * 2 + 1] = rq[0];
    }
}

// ========= K2: GN+GELU -> x1b  |  MFMA inproj -> xpad (fp16)  |  ring zero =========
__global__ void k_mid(const unsigned short* __restrict__ xcb, const float* __restrict__ partials,
                      const float* __restrict__ gn_w, const float* __restrict__ gn_b,
                      unsigned short* __restrict__ x1b,
                      const unsigned short* __restrict__ x_tb,
                      const unsigned short* __restrict__ inpB,
                      const float* __restrict__ inp_b,
                      unsigned short* __restrict__ xpad) {
    int bb = blockIdx.x, tid = threadIdx.x;
    if (bb < 512) {                              // ---- GroupNorm(1,C)+GELU, transposed ----
        __shared__ float rs[256], rq[256];
        __shared__ unsigned short tile[64][66];
        float a = 0.f, b = 0.f;
        for (int i = tid; i < 8192; i += 256) { a += partials[2 * i]; b += partials[2 * i + 1]; }
        rs[tid] = a; rq[tid] = b;
        __syncthreads();
        for (int off = 128; off > 0; off >>= 1) {
            if (tid < off) { rs[tid] += rs[tid + off]; rq[tid] += rq[tid + off]; }
            __syncthreads();
        }
        const float Minv = 1.f / 2097152.f;
        float mu = rs[0] * Minv;
        float var = rq[0] * Minv - mu * mu;
        float rsq = rsqrtf(var + 1e-5f);
        int s0 = bb * 64;
        int row = tid >> 6, lane = tid & 63;
        for (int c = row; c < 64; c += 4) {
            float v = (b2f1(xcb[(size_t)c * SP + s0 + lane]) - mu) * rsq * gn_w[c] + gn_b[c];
            // gelu(tanh) = v * sigmoid(2t), t = 0.79788456*(v+0.044715 v^3)
            float t2 = 1.5957691216057308f * (v + 0.044715f * v * v * v);
            tile[c][lane] = f2b(v / (1.f + __expf(-t2)));
        }
        __syncthreads();
        for (int r = row; r < 64; r += 4)
            x1b[(size_t)(s0 + r) * 64 + lane] = tile[lane][r];
        return;
    }
    if (bb < 1024) {                             // ---- inproj: 4 waves x 16 voxels ----
        int wv = tid >> 6, lane = tid & 63;
        int quad = lane >> 4, col = lane & 15;
        int s0 = (bb - 512) * 64 + wv * 16;
        bf16x8 a0 = *(const bf16x8*)(x_tb + (size_t)(s0 + col) * 64 + quad * 8);
        bf16x8 a1 = *(const bf16x8*)(x_tb + (size_t)(s0 + col) * 64 + 32 + quad * 8);
        int vp[4];
#pragma unroll
        for (int r = 0; r < 4; ++r) {
            int s = s0 + (quad << 2) + r;        // orig voxel (d,h,w) at 38-coord +2
            vp[r] = (((s >> 10) + 2) * PW + ((s >> 5) & 31) + 2) * PW + (s & 31) + 2;
        }
#pragma unroll
        for (int nt = 0; nt < 4; ++nt) {
            int n0 = nt * 16;
            bf16x8 b0 = *(const bf16x8*)(inpB + (n0 + col) * 64 + quad * 8);
            bf16x8 b1 = *(const bf16x8*)(inpB + (n0 + col) * 64 + 32 + quad * 8);
            f32x4 c = {0.f, 0.f, 0.f, 0.f};
            c = __builtin_amdgcn_mfma_f32_16x16x32_bf16(a0, b0, c, 0, 0, 0);
            c = __builtin_amdgcn_mfma_f32_16x16x32_bf16(a1, b1, c, 0, 0, 0);
            float bq = inp_b[n0 + col];
#pragma unroll
            for (int r = 0; r < 4; ++r)
                xpad[(size_t)vp[r] * 64 + n0 + col] =
                    __half_as_ushort(__float2half(c[r] + bq));
        }
        return;
    }
    // ---- ring zero (fp16): 16 voxels x 16 8-byte slots per 256 threads, 4 iters ----
    int cblk = bb - 1024;
    int j = tid >> 4, c4 = tid & 15;
    u16x4 z = {0, 0, 0, 0};
#pragma unroll
    for (int k = 0; k < 4; ++k) {
        int v = cblk * 64 + k * 16 + j;
        if (v >= PVOX) break;
        int zz = v / PW2, r = v - zz * PW2, yy = r / PW, xx = r - yy * PW;
        if (zz < 2 || zz > 33 || yy < 2 || yy > 33 || xx < 2 || xx > 33)
            *(u16x4*)(xpad + (size_t)v * 64 + c4 * 4) = z;
    }
}

// ---- unrolled 14-point sampler; P0 makes px/py/pz compile-time ----
template<int P0>
__device__ __forceinline__ void sample14(const float* __restrict__ orow,
                                         const float* __restrict__ mrow,
                                         const char* __restrict__ volc,
                                         float xb, float yb, float zb,
                                         float* __restrict__ acc) {
#pragma unroll
    for (int i = 0; i < 14; ++i) {
        const int p = P0 + i;
        const int px = p % 3, py = (p / 3) % 3, pz = p / 9;   // p=27 -> (0,0,3) dummy
        float ox = orow[p * 3 + 0], oy = orow[p * 3 + 1], oz = orow[p * 3 + 2];
        float mk = mrow[p];
        float ix = __builtin_fmaf(0.25f, ox, xb + (float)px);
        float iy = __builtin_fmaf(0.5f, oy, yb + (float)py);
        float iz = __builtin_fmaf(0.5f, oz, zb + (float)pz);
        // clamp to [0,36]: OOB samples land wholly in the zero ring
        ix = fminf(fmaxf(ix, 0.f), 36.f);
        iy = fminf(fmaxf(iy, 0.f), 36.f);
        iz = fminf(fmaxf(iz, 0.f), 36.f);
        float xf = floorf(ix), yf = floorf(iy), zf = floorf(iz);
        float fx = ix - xf, fy = iy - yf, fz = iz - zf;
        float fi = __builtin_fmaf(zf, (float)PW2, __builtin_fmaf(yf, (float)PW, xf));
        int ib = ((int)fi) << 7;                 // 128 B per voxel row (fp16)
        const char* base = volc + ib;
        uint4 r000 = *(const uint4*)(base);
        uint4 r001 = *(const uint4*)(base + 128);
        uint4 r010 = *(const uint4*)(base + PW * 128);
        uint4 r011 = *(const uint4*)(base + PW * 128 + 128);
        uint4 r100 = *(const uint4*)(base + PW2 * 128);
        uint4 r101 = *(const uint4*)(base + PW2 * 128 + 128);
        uint4 r110 = *(const uint4*)(base + (PW2 + PW) * 128);
        uint4 r111 = *(const uint4*)(base + (PW2 + PW) * 128 + 128);
        __half2 fx2 = __float2half2_rn(fx);
        __half2 fy2 = __float2half2_rn(fy);
        __half2 fz2 = __float2half2_rn(fz);
        #define TRI(comp, ci)                                                   \
        {                                                                       \
            __half2 t0 = __hfma2(fx2, __hsub2(h2(r001.comp), h2(r000.comp)), h2(r000.comp)); \
            __half2 t1 = __hfma2(fx2, __hsub2(h2(r011.comp), h2(r010.comp)), h2(r010.comp)); \
            __half2 t2 = __hfma2(fx2, __hsub2(h2(r101.comp), h2(r100.comp)), h2(r100.comp)); \
            __half2 t3 = __hfma2(fx2, __hsub2(h2(r111.comp), h2(r110.comp)), h2(r110.comp)); \
            __half2 u0 = __hfma2(fy2, __hsub2(t1, t0), t0);                     \
            __half2 u1 = __hfma2(fy2, __hsub2(t3, t2), t2);                     \
            __half2 rr = __hfma2(fz2, __hsub2(u1, u0), u0);                     \
            float2 ff = __half22float2(rr);                                     \
            acc[2 * ci + 0] = __builtin_fmaf(mk, ff.x, acc[2 * ci + 0]);        \
            acc[2 * ci + 1] = __builtin_fmaf(mk, ff.y, acc[2 * ci + 1]);        \
        }
        TRI(x, 0) TRI(y, 1) TRI(z, 2) TRI(w, 3)
        #undef TRI
    }
}

// ========= K3: main — 16 vox/block, point-halves split across wave pairs =========
__global__ void __launch_bounds__(256, 8) k_main(const unsigned short* __restrict__ x1b,
                                                 const unsigned short* __restrict__ xpad,
                                                 const unsigned short* __restrict__ WcatB,
                                                 const float* __restrict__ bcat,
                                                 const unsigned short* __restrict__ outB,
                                                 const float* __restrict__ out_b,
                                                 float* __restrict__ out) {
    __shared__ float om_s[16 * OMS];             // 28-pt padded offs+masks; obuf in epilogue
    __shared__ unsigned short smb[16 * 80];      // sampled accum, bf16 (stride 80 for 16B align)
    __shared__ float pbuf[16 * 64];              // f32 partials from point-half 1 (4 KB)
    int tid = threadIdx.x, wv = tid >> 6, lane = tid & 63;
    int quad = lane >> 4, col = lane & 15;
    // XCD swizzle: blocks sharing (blk&7) land on one XCD, contiguous 4096-voxel slab
    int sb = ((blockIdx.x & 7) << 8) | (blockIdx.x >> 3);
    int s0 = sb * 16;                            // 16 voxels per block
    // ---- phase 1: offset+mask GEMM (16x64)@(64x224); 14 jt tiles over 4 waves ----
    {
        bf16x8 a0 = *(const bf16x8*)(x1b + (size_t)(s0 + col) * 64 + quad * 8);
        bf16x8 a1 = *(const bf16x8*)(x1b + (size_t)(s0 + col) * 64 + 32 + quad * 8);
        for (int jt = wv; jt < 14; jt += 4) {
            int n0 = jt * 16;
            bf16x8 b0 = *(const bf16x8*)(WcatB + (n0 + col) * 64 + quad * 8);
            bf16x8 b1 = *(const bf16x8*)(WcatB + (n0 + col) * 64 + 32 + quad * 8);
            f32x4 c = {0.f, 0.f, 0.f, 0.f};
            c = __builtin_amdgcn_mfma_f32_16x16x32_bf16(a0, b0, c, 0, 0, 0);
            c = __builtin_amdgcn_mfma_f32_16x16x32_bf16(a1, b1, c, 0, 0, 0);
            float bb = bcat[n0 + col];
            // remap feature n -> padded 28-pt slot
            int n = n0 + col, slot;
            if (n < 162) slot = n + ((n >= 81) ? 3 : 0);
            else { int n2 = n - 162; slot = 168 + n2 + ((n2 >= 27) ? 1 : 0); }
            if (n < 216) {
#pragma unroll
                for (int r = 0; r < 4; ++r)
                    om_s[(quad * 4 + r) * OMS + slot] = c[r] + bb;
            }
        }
    }
    __syncthreads();
    // ---- phase 2: softmax over 27 pts, 32 rows = 16 voxels x 2 groups; pad pt 27 ----
    if (tid < 32) {
        int v = tid >> 1, g = tid & 1;
        float* m = &om_s[v * OMS + 168 + g * 28];
        float mx = m[0];
#pragma unroll
        for (int p = 1; p < 27; ++p) mx = fmaxf(mx, m[p]);
        float e[27]; float sm = 0.f;
#pragma unroll
        for (int p = 0; p < 27; ++p) { e[p] = __expf(m[p] - mx); sm += e[p]; }
        float inv = 1.f / sm;
#pragma unroll
        for (int p = 0; p < 27; ++p) m[p] = e[p] * inv;
        m[27] = 0.f;                             // dummy point: zero mask
        float* o = &om_s[v * OMS + g * 84];      // dummy point: zero offsets
        o[81] = 0.f; o[82] = 0.f; o[83] = 0.f;
    }
    __syncthreads();
    // ---- phase 3: sampling; wave = (voxel-half vh, point-half ph) ----
    {
        int vh = wv >> 1, ph = wv & 1;
        int v = (vh << 3) | (lane >> 3);         // local voxel 0..15
        int oct = lane & 7, gg = oct >> 2;       // channels oct*8..oct*8+7
        int sv = s0 + v;
        int d = sv >> 10, h = (sv >> 5) & 31, w = sv & 31;
        float zb = (float)(d + 1), yb = (float)(h + 1), xb = (float)(w + 1);
        const float* orow = &om_s[v * OMS + gg * 84];
        const float* mrow = &om_s[v * OMS + 168 + gg * 28];
        const char* volc = (const char*)xpad + oct * 16;    // 8 fp16 channels
        float acc[8] = {0.f, 0.f, 0.f, 0.f, 0.f, 0.f, 0.f, 0.f};
        if (ph == 0) sample14<0>(orow, mrow, volc, xb, yb, zb, acc);
        else         sample14<14>(orow, mrow, volc, xb, yb, zb, acc);
        if (ph == 1) {                           // stash f32 partial
            float* pp = &pbuf[v * 64 + oct * 8];
            *(f32x4*)(pp) = *(f32x4*)(acc);
            *(f32x4*)(pp + 4) = *(f32x4*)(acc + 4);
        }
        __syncthreads();
        if (ph == 0) {                           // combine + pack bf16
            const float* pp = &pbuf[v * 64 + oct * 8];
            bf16x8 sb8;
#pragma unroll
            for (int k = 0; k < 8; ++k) sb8[k] = (short)f2b(acc[k] + pp[k]);
            *(bf16x8*)(smb + v * 80 + oct * 8) = sb8;
        }
    }
    __syncthreads();
    // ---- phase 4: out projection (16x64)@(64x64); wave wv does col tile wv ----
    {
        float* obuf = om_s;                      // alias: om_s is dead now
        int n0 = wv * 16;
        bf16x8 oa0 = *(const bf16x8*)(smb + col * 80 + quad * 8);
        bf16x8 oa1 = *(const bf16x8*)(smb + col * 80 + 32 + quad * 8);
        bf16x8 b0 = *(const bf16x8*)(outB + (n0 + col) * 64 + quad * 8);
        bf16x8 b1 = *(const bf16x8*)(outB + (n0 + col) * 64 + 32 + quad * 8);
        f32x4 c = {0.f, 0.f, 0.f, 0.f};
        c = __builtin_amdgcn_mfma_f32_16x16x32_bf16(oa0, b0, c, 0, 0, 0);
        c = __builtin_amdgcn_mfma_f32_16x16x32_bf16(oa1, b1, c, 0, 0, 0);
        float bb = out_b[n0 + col];
#pragma unroll
        for (int r = 0; r < 4; ++r)
            obuf[(quad * 4 + r) * 64 + n0 + col] = c[r] + bb;
    }
    __syncthreads();
    // ---- phase 5: coalesced output store (16 rows x 256 B contiguous) ----
    {
        const float* obuf = om_s;
#pragma unroll
        for (int i = 0; i < 4; ++i) {
            int idx = i * 256 + tid;
            out[(size_t)(s0 + (idx >> 6)) * 64 + (idx & 63)] = obuf[idx];
        }
    }
}

extern "C" void kernel_launch(void* const* d_in, const int* in_sizes, int n_in,
                              void* d_out, int out_size, void* d_ws, size_t ws_size,
                              hipStream_t stream) {
    const float* x      = (const float*)d_in[0];
    const float* dw_w   = (const float*)d_in[1];
    const float* gn_w   = (const float*)d_in[2];
    const float* gn_b   = (const float*)d_in[3];
    const float* inp_w  = (const float*)d_in[4];
    const float* inp_b  = (const float*)d_in[5];
    const float* off_w  = (const float*)d_in[6];
    const float* off_b  = (const float*)d_in[7];
    const float* mask_w = (const float*)d_in[8];
    const float* mask_b = (const float*)d_in[9];
    const float* out_w  = (const float*)d_in[10];
    const float* out_b  = (const float*)d_in[11];

    char* B = (char*)d_ws;
    float*          partials = (float*)(B + 256);                // 64 KB
    unsigned short* xcb      = (unsigned short*)(B + 65792);     // 4 MB (bf16)
    unsigned short* x1b      = (unsigned short*)(B + 8454400);   // 4 MB
    unsigned short* x_tb     = (unsigned short*)(B + 12648704);  // 4 MB
    unsigned short* xpad     = (unsigned short*)(B + 16843008);  // 7.02 MB (fp16)
    unsigned short* WcatB    = (unsigned short*)(B + 30890240);  // 28 KB
    float*          bcat     = (float*)(B + 30918912);           // 1 KB
    unsigned short* inpB     = (unsigned short*)(B + 30919936);  // 8 KB
    unsigned short* outB     = (unsigned short*)(B + 30928128);  // 8 KB
    float* out = (float*)d_out;

    k_front<<<8792, 256, 0, stream>>>(x, dw_w, off_w, mask_w, off_b, mask_b,
                                      inp_w, out_w, WcatB, bcat, inpB, outB,
                                      x_tb, xcb, partials);
    k_mid<<<512 + 512 + 858, 256, 0, stream>>>(xcb, partials, gn_w, gn_b, x1b,
                                               x_tb, inpB, inp_b, xpad);
    k_main<<<2048, 256, 0, stream>>>(x1b, xpad, WcatB, bcat, outB, out_b, out);
}